// Round 21
// baseline (193.556 us; speedup 1.0000x reference)
//
#include <hip/hip_runtime.h>
#include <stdint.h>

// ---------------------------------------------------------------------------
// Fused LSTM cell, round 21 = round 20 (champion, 189.7us) + two micro-edits:
//   (1) s_setprio(1) around the MFMA cluster -- r20 runs 2 independent
//       drifting blocks/CU (role diversity), unlike m190's lockstep null.
//   (2) C-prefetch S==8 -> S==7 (one more phase of cover), FIFO recount:
//       VMW 6 x8, 38, 38, 6, 0.
//  prep_all: xb[131072][128] bf16 (pad, k127=1.0 bias driver),
//            hb[131072][256] bf16, Bt 16-k fragment units (bias @ k127).
//  lstm_main: 256 thr (4 waves = 2wr x 2wc), tile 128 rows x 256 gate-cols,
//    12 stages BK=32, mfma_f32_32x32x16_bf16, 6 gl_lds/wave/stage
//    (2A+4B homogeneous FIFO), 3-deep LDS multibuffer (72 KiB), counted
//    vmcnt, single barrier/step, full-128B-line NT stores.
// ---------------------------------------------------------------------------

typedef short bf16x8 __attribute__((ext_vector_type(8)));
typedef float f32x16 __attribute__((ext_vector_type(16)));

#define HDIM   256
#define INDIM  100
#define NROWS  131072
// d_ws layout (ushort offsets): Bt @0 (768 KiB), xb @1 MiB, hb @34 MiB
#define BT_OFF 0
#define XB_OFF (1048576 / 2)
#define HB_OFF (35651584 / 2)
#define ABUF(b) ((b) * 8192)
#define BBUF(b) (24576 + (b) * 16384)

__device__ __forceinline__ float fexp(float x) {
  return __builtin_amdgcn_exp2f(x * 1.44269504088896340736f);
}
__device__ __forceinline__ float frcp(float x) { return __builtin_amdgcn_rcpf(x); }
__device__ __forceinline__ float sigm(float x) { return frcp(1.0f + fexp(-x)); }
__device__ __forceinline__ float tanh_fast(float x) {
  return 1.0f - 2.0f * frcp(1.0f + fexp(2.0f * x));
}
__device__ __forceinline__ unsigned short f2bf_rne(float f) {
  union { float f; uint32_t u; } v; v.f = f;
  return (unsigned short)((v.u + 0x7FFFu + ((v.u >> 16) & 1u)) >> 16);
}
__device__ __forceinline__ void gl16(const void* g, void* l) {
  __builtin_amdgcn_global_load_lds(
      (const __attribute__((address_space(1))) unsigned int*)g,
      (__attribute__((address_space(3))) unsigned int*)l, 16, 0, 0);
}
#define VMW(N) asm volatile("s_waitcnt vmcnt(" #N ")" ::: "memory")

// ---- prep: 3 jobs ----------------------------------------------------------
__global__ void prep_all(const float* __restrict__ X, const float* __restrict__ Hin,
                         const float* __restrict__ Wx, const float* __restrict__ Wh,
                         const float* __restrict__ bxp, const float* __restrict__ bhp,
                         unsigned short* __restrict__ ws) {
  const int b = blockIdx.x, tid = threadIdx.x;
  if (b < 8192) {                        // ---- x -> xb[131072][128] ----
    const int t   = b * 256 + tid;
    const int row = t >> 4, k0 = (t & 15) * 8;
    const float* xp = X + (size_t)row * INDIM;
    float4 lo = make_float4(0.f, 0.f, 0.f, 0.f);
    float4 hi = make_float4(0.f, 0.f, 0.f, 0.f);
    if (k0 + 4 <= INDIM) lo = *reinterpret_cast<const float4*>(xp + k0);
    if (k0 + 8 <= INDIM) hi = *reinterpret_cast<const float4*>(xp + k0 + 4);
    float va[8] = {lo.x, lo.y, lo.z, lo.w, hi.x, hi.y, hi.z, hi.w};
    unsigned short o[8];
#pragma unroll
    for (int e = 0; e < 8; ++e) {
      const int k = k0 + e;
      const float f = (k < INDIM) ? va[e] : (k == 127 ? 1.0f : 0.0f);
      o[e] = f2bf_rne(f);
    }
    *reinterpret_cast<bf16x8*>(ws + XB_OFF + (size_t)row * 128 + k0) =
        *reinterpret_cast<bf16x8*>(o);
  } else if (b < 24576) {                // ---- h -> hb[131072][256] ----
    const int t   = (b - 8192) * 256 + tid;
    const int row = t >> 5, k0 = (t & 31) * 8;
    const float* hp = Hin + (size_t)row * HDIM + k0;
    const float4 lo = *reinterpret_cast<const float4*>(hp);
    const float4 hi = *reinterpret_cast<const float4*>(hp + 4);
    unsigned short o[8] = {f2bf_rne(lo.x), f2bf_rne(lo.y), f2bf_rne(lo.z),
                           f2bf_rne(lo.w), f2bf_rne(hi.x), f2bf_rne(hi.y),
                           f2bf_rne(hi.z), f2bf_rne(hi.w)};
    *reinterpret_cast<bf16x8*>(ws + HB_OFF + (size_t)row * 256 + k0) =
        *reinterpret_cast<bf16x8*>(o);
  } else {                               // ---- W -> Bt blob, 16-k units ----
    const int unit = (b - 24576) * 4 + (tid >> 6);   // 0..767
    const int lane = tid & 63;
    const int kst  = unit % 24;          // 16-k step 0..23
    const int g    = (unit / 24) & 3;    // gate
    const int hb32 = unit / 96;          // 0..7 (32 H-col block)
    const int wcol = g * HDIM + hb32 * 32 + (lane & 31);
    const int kb   = kst * 16 + (lane >> 5) * 8;
    unsigned short v[8];
#pragma unroll
    for (int e = 0; e < 8; ++e) {
      const int k = kb + e;              // 0..383
      float f = 0.0f;
      if (k < INDIM)     f = Wx[(size_t)k * 1024 + wcol];
      else if (k == 127) f = bxp[wcol] + bhp[wcol];
      else if (k >= 128) f = Wh[(size_t)(k - 128) * 1024 + wcol];
      v[e] = f2bf_rne(f);
    }
    *reinterpret_cast<bf16x8*>(ws + BT_OFF + (size_t)unit * 512 + lane * 8) =
        *reinterpret_cast<bf16x8*>(v);
  }
}

// ---- main -------------------------------------------------------------------
__global__ __launch_bounds__(256, 2)
void lstm_main(const unsigned short* __restrict__ ws,
               const float* __restrict__ Cin, float* __restrict__ out)
{
  __shared__ unsigned char smem[73728];  // 3 x (8K A + 16K B)

  const int tid  = threadIdx.x;
  const int orig = blockIdx.x;           // 0..4095 (%8==0 -> bijective)
  const int lg   = ((orig & 7) << 9) | (orig >> 3);
  const int mt   = lg >> 2;              // M tile 0..1023 (128 rows)
  const int bnn  = lg & 3;               // N tile 0..3 (64 H-cols)

  const int lane = tid & 63;
  const int l31  = lane & 31;
  const int kh   = lane >> 5;            // k-half of fragment
  const int wid  = tid >> 6;             // 0..3
  const int wr   = wid >> 1;             // 0..1: 64-row group
  const int wc   = wid & 1;              // 0..1: 32-hcol half
  const int ch   = bnn * 64 + wc * 32 + l31;
  const int sx   = (l31 >> 1) & 3;       // read-side XOR (== (row>>1)&3)

  const unsigned short* xb = ws + XB_OFF;
  const unsigned short* hb = ws + HB_OFF;
  const unsigned short* Bt = ws + BT_OFF;

  // A staging: 2 gl_lds/wave/stage (layout/swizzle identical to r19/r20)
  const unsigned short* xsrc[2];
  const unsigned short* hsrc[2];
#pragma unroll
  for (int j = 0; j < 2; ++j) {
    const int ci = (wid * 2 + j) * 64 + lane;      // 0..511
    const int r  = ci >> 2;                        // tile row 0..127
    const int sc = (ci & 3) ^ ((r >> 1) & 3);      // pre-swizzled chunk
    xsrc[j] = xb + (size_t)(mt * 128 + r) * 128 + sc * 8;
    hsrc[j] = hb + (size_t)(mt * 128 + r) * 256 + sc * 8;
  }
  const int ad0 = (wid * 2 + 0) * 1024;
  const int ad1 = (wid * 2 + 1) * 1024;

  // B staging: 4 gl_lds/wave/stage; local unit lu = wid*4+j (0..15),
  // lu = nb*8 + g*2 + kk; global unit = ((bnn*2+nb)*4+g)*24 + 2S+kk.
  const unsigned short* bsrc[4];
#pragma unroll
  for (int j = 0; j < 4; ++j) {
    const int lu = wid * 4 + j;
    const int nb = lu >> 3, g = (lu >> 1) & 3, kk = lu & 1;
    bsrc[j] = Bt + ((size_t)(((bnn * 2 + nb) * 4 + g) * 24) + kk) * 512 +
              lane * 8;
  }

  f32x16 acc[2][4];                      // [m][gate], 128 VGPR
#pragma unroll
  for (int m = 0; m < 2; ++m)
#pragma unroll
    for (int g = 0; g < 4; ++g)
#pragma unroll
      for (int e = 0; e < 16; ++e) acc[m][g][e] = 0.0f;

  float cvv[2][16];

  auto STAGE = [&](int T) {
    char* Ad = (char*)smem + ABUF(T % 3);
    char* Bd = (char*)smem + BBUF(T % 3);
    if (T < 4) {
      gl16(xsrc[0] + T * 32, Ad + ad0);
      gl16(xsrc[1] + T * 32, Ad + ad1);
    } else {
      gl16(hsrc[0] + (T - 4) * 32, Ad + ad0);
      gl16(hsrc[1] + (T - 4) * 32, Ad + ad1);
    }
#pragma unroll
    for (int j = 0; j < 4; ++j)
      gl16(bsrc[j] + T * 1024, Bd + (wid * 4 + j) * 1024);
  };

  auto COMPUTE = [&](int S) {
    const unsigned short* Ab = (const unsigned short*)(smem + ABUF(S % 3));
    const unsigned short* Bb = (const unsigned short*)(smem + BBUF(S % 3));
#pragma unroll
    for (int kk = 0; kk < 2; ++kk) {
      bf16x8 afr[2], bfr[4];
#pragma unroll
      for (int m = 0; m < 2; ++m) {
        const int row   = wr * 64 + m * 32 + l31;
        const int chunk = (kk * 2 + kh) ^ sx;
        afr[m] = *reinterpret_cast<const bf16x8*>(Ab + row * 32 + chunk * 8);
      }
#pragma unroll
      for (int g = 0; g < 4; ++g) {
        const int u = wc * 8 + g * 2 + kk;
        bfr[g] = *reinterpret_cast<const bf16x8*>(Bb + u * 512 + lane * 8);
      }
      __builtin_amdgcn_s_setprio(1);
#pragma unroll
      for (int m = 0; m < 2; ++m)
#pragma unroll
        for (int g = 0; g < 4; ++g)
          acc[m][g] = __builtin_amdgcn_mfma_f32_32x32x16_bf16(
              afr[m], bfr[g], acc[m][g], 0, 0, 0);
      __builtin_amdgcn_s_setprio(0);
    }
  };

  // prologue: 2 stages (12 gl_lds) in flight
  STAGE(0);
  STAGE(1);

  // FIFO (6 gl_lds/stage/wave): steady VMW(6). C (32 loads) issued at end of
  // step 7 (after STAGE(9)):
  //   step 8 top:  outstanding S8,S9,C      -> need S8  -> VMW(38)
  //   step 9 top:  outstanding S9,C,S10     -> need S9  -> VMW(38)
  //   step 10 top: outstanding C,S10,S11    -> need S10 -> VMW(6) (drains C)
  //   step 11 top: outstanding S11          -> VMW(0). Epilogue: free.
#define STEP(S, KN)                                                \
  do {                                                             \
    VMW(KN);                                                       \
    __builtin_amdgcn_s_barrier();                                  \
    if ((S) + 2 < 12) STAGE((S) + 2);                              \
    if ((S) == 7) {                                                \
      const float* cb =                                            \
          Cin + ((size_t)mt * 128 + wr * 64 + 4 * kh) * HDIM + ch; \
      _Pragma("unroll")                                            \
      for (int m = 0; m < 2; ++m)                                  \
        _Pragma("unroll")                                          \
        for (int rg = 0; rg < 16; ++rg) {                          \
          const int roff = m * 32 + (rg & 3) + 8 * (rg >> 2);      \
          cvv[m][rg] = __builtin_nontemporal_load(                 \
              cb + (size_t)roff * HDIM);                           \
        }                                                          \
    }                                                              \
    COMPUTE(S);                                                    \
  } while (0)

  STEP(0, 6);  STEP(1, 6);  STEP(2, 6);  STEP(3, 6);
  STEP(4, 6);  STEP(5, 6);  STEP(6, 6);  STEP(7, 6);
  STEP(8, 38); STEP(9, 38); STEP(10, 6); STEP(11, 0);
#undef STEP

  // ---- epilogue: bias folded in acc; lane-local gate combine --------------
  // D: col = lane&31, row = (reg&3) + 8*(reg>>2) + 4*kh (+ m*32)
  // -> 32 consecutive lanes store 128B full lines.
  float* op  = out + ((size_t)mt * 128 + wr * 64 + 4 * kh) * HDIM + ch;
  float* op2 = op + (size_t)NROWS * HDIM;
#pragma unroll
  for (int m = 0; m < 2; ++m) {
#pragma unroll
    for (int rg = 0; rg < 16; ++rg) {
      const int roff = m * 32 + (rg & 3) + 8 * (rg >> 2);
      const float pi = acc[m][0][rg];
      const float pf = acc[m][1][rg];
      const float pg = acc[m][2][rg];
      const float po = acc[m][3][rg];
      const float ig = sigm(pi), fg = sigm(pf);
      const float gg = tanh_fast(pg), og = sigm(po);
      const float co = fg * cvv[m][rg] + ig * gg;
      const float ho = og * tanh_fast(co);
      __builtin_nontemporal_store(co, op  + (size_t)roff * HDIM);
      __builtin_nontemporal_store(ho, op2 + (size_t)roff * HDIM);
    }
  }
}

extern "C" void kernel_launch(void* const* d_in, const int* in_sizes, int n_in,
                              void* d_out, int out_size, void* d_ws, size_t ws_size,
                              hipStream_t stream) {
  const float* x  = (const float*)d_in[0];
  const float* C  = (const float*)d_in[1];
  const float* h  = (const float*)d_in[2];
  const float* Wx = (const float*)d_in[3];
  const float* Wh = (const float*)d_in[4];
  const float* bx = (const float*)d_in[5];
  const float* bh = (const float*)d_in[6];
  float* o = (float*)d_out;
  unsigned short* ws = (unsigned short*)d_ws;   // ~98 MiB used

  prep_all<<<dim3(24768), dim3(256), 0, stream>>>(x, h, Wx, Wh, bx, bh, ws);
  lstm_main<<<dim3(4096), dim3(256), 0, stream>>>(ws, C, o);
}

// Round 22
// 188.229 us; speedup vs baseline: 1.0283x; 1.0283x over previous
//
#include <hip/hip_runtime.h>
#include <stdint.h>

// ---------------------------------------------------------------------------
// Fused LSTM cell, FINAL = round 20 champion (189.7us), restored exactly.
//  prep_all: xb[131072][128] bf16 (pad, k127=1.0 bias driver),
//            hb[131072][256] bf16, Bt 16-k fragment units (bias @ k127).
//  lstm_main: 256 thr (4 waves = 2wr x 2wc), tile 128 rows x 256 gate-cols,
//    12 stages BK=32, mfma_f32_32x32x16_bf16, 6 gl_lds/wave/stage
//    (2A+4B homogeneous FIFO), 3-deep LDS multibuffer (72 KiB), counted
//    vmcnt (VMW(6) steady, 38/38/0 C-tail), single barrier/step,
//    full-128B-line NT stores from the 32x32 D layout.
// ---------------------------------------------------------------------------

typedef short bf16x8 __attribute__((ext_vector_type(8)));
typedef float f32x16 __attribute__((ext_vector_type(16)));

#define HDIM   256
#define INDIM  100
#define NROWS  131072
// d_ws layout (ushort offsets): Bt @0 (768 KiB), xb @1 MiB, hb @34 MiB
#define BT_OFF 0
#define XB_OFF (1048576 / 2)
#define HB_OFF (35651584 / 2)
#define ABUF(b) ((b) * 8192)
#define BBUF(b) (24576 + (b) * 16384)

__device__ __forceinline__ float fexp(float x) {
  return __builtin_amdgcn_exp2f(x * 1.44269504088896340736f);
}
__device__ __forceinline__ float frcp(float x) { return __builtin_amdgcn_rcpf(x); }
__device__ __forceinline__ float sigm(float x) { return frcp(1.0f + fexp(-x)); }
__device__ __forceinline__ float tanh_fast(float x) {
  return 1.0f - 2.0f * frcp(1.0f + fexp(2.0f * x));
}
__device__ __forceinline__ unsigned short f2bf_rne(float f) {
  union { float f; uint32_t u; } v; v.f = f;
  return (unsigned short)((v.u + 0x7FFFu + ((v.u >> 16) & 1u)) >> 16);
}
__device__ __forceinline__ void gl16(const void* g, void* l) {
  __builtin_amdgcn_global_load_lds(
      (const __attribute__((address_space(1))) unsigned int*)g,
      (__attribute__((address_space(3))) unsigned int*)l, 16, 0, 0);
}
#define VMW(N) asm volatile("s_waitcnt vmcnt(" #N ")" ::: "memory")

// ---- prep: 3 jobs ----------------------------------------------------------
__global__ void prep_all(const float* __restrict__ X, const float* __restrict__ Hin,
                         const float* __restrict__ Wx, const float* __restrict__ Wh,
                         const float* __restrict__ bxp, const float* __restrict__ bhp,
                         unsigned short* __restrict__ ws) {
  const int b = blockIdx.x, tid = threadIdx.x;
  if (b < 8192) {                        // ---- x -> xb[131072][128] ----
    const int t   = b * 256 + tid;
    const int row = t >> 4, k0 = (t & 15) * 8;
    const float* xp = X + (size_t)row * INDIM;
    float4 lo = make_float4(0.f, 0.f, 0.f, 0.f);
    float4 hi = make_float4(0.f, 0.f, 0.f, 0.f);
    if (k0 + 4 <= INDIM) lo = *reinterpret_cast<const float4*>(xp + k0);
    if (k0 + 8 <= INDIM) hi = *reinterpret_cast<const float4*>(xp + k0 + 4);
    float va[8] = {lo.x, lo.y, lo.z, lo.w, hi.x, hi.y, hi.z, hi.w};
    unsigned short o[8];
#pragma unroll
    for (int e = 0; e < 8; ++e) {
      const int k = k0 + e;
      const float f = (k < INDIM) ? va[e] : (k == 127 ? 1.0f : 0.0f);
      o[e] = f2bf_rne(f);
    }
    *reinterpret_cast<bf16x8*>(ws + XB_OFF + (size_t)row * 128 + k0) =
        *reinterpret_cast<bf16x8*>(o);
  } else if (b < 24576) {                // ---- h -> hb[131072][256] ----
    const int t   = (b - 8192) * 256 + tid;
    const int row = t >> 5, k0 = (t & 31) * 8;
    const float* hp = Hin + (size_t)row * HDIM + k0;
    const float4 lo = *reinterpret_cast<const float4*>(hp);
    const float4 hi = *reinterpret_cast<const float4*>(hp + 4);
    unsigned short o[8] = {f2bf_rne(lo.x), f2bf_rne(lo.y), f2bf_rne(lo.z),
                           f2bf_rne(lo.w), f2bf_rne(hi.x), f2bf_rne(hi.y),
                           f2bf_rne(hi.z), f2bf_rne(hi.w)};
    *reinterpret_cast<bf16x8*>(ws + HB_OFF + (size_t)row * 256 + k0) =
        *reinterpret_cast<bf16x8*>(o);
  } else {                               // ---- W -> Bt blob, 16-k units ----
    const int unit = (b - 24576) * 4 + (tid >> 6);   // 0..767
    const int lane = tid & 63;
    const int kst  = unit % 24;          // 16-k step 0..23
    const int g    = (unit / 24) & 3;    // gate
    const int hb32 = unit / 96;          // 0..7 (32 H-col block)
    const int wcol = g * HDIM + hb32 * 32 + (lane & 31);
    const int kb   = kst * 16 + (lane >> 5) * 8;
    unsigned short v[8];
#pragma unroll
    for (int e = 0; e < 8; ++e) {
      const int k = kb + e;              // 0..383
      float f = 0.0f;
      if (k < INDIM)     f = Wx[(size_t)k * 1024 + wcol];
      else if (k == 127) f = bxp[wcol] + bhp[wcol];
      else if (k >= 128) f = Wh[(size_t)(k - 128) * 1024 + wcol];
      v[e] = f2bf_rne(f);
    }
    *reinterpret_cast<bf16x8*>(ws + BT_OFF + (size_t)unit * 512 + lane * 8) =
        *reinterpret_cast<bf16x8*>(v);
  }
}

// ---- main -------------------------------------------------------------------
__global__ __launch_bounds__(256, 2)
void lstm_main(const unsigned short* __restrict__ ws,
               const float* __restrict__ Cin, float* __restrict__ out)
{
  __shared__ unsigned char smem[73728];  // 3 x (8K A + 16K B)

  const int tid  = threadIdx.x;
  const int orig = blockIdx.x;           // 0..4095 (%8==0 -> bijective)
  const int lg   = ((orig & 7) << 9) | (orig >> 3);
  const int mt   = lg >> 2;              // M tile 0..1023 (128 rows)
  const int bnn  = lg & 3;               // N tile 0..3 (64 H-cols)

  const int lane = tid & 63;
  const int l31  = lane & 31;
  const int kh   = lane >> 5;            // k-half of fragment
  const int wid  = tid >> 6;             // 0..3
  const int wr   = wid >> 1;             // 0..1: 64-row group
  const int wc   = wid & 1;              // 0..1: 32-hcol half
  const int ch   = bnn * 64 + wc * 32 + l31;
  const int sx   = (l31 >> 1) & 3;       // read-side XOR (== (row>>1)&3)

  const unsigned short* xb = ws + XB_OFF;
  const unsigned short* hb = ws + HB_OFF;
  const unsigned short* Bt = ws + BT_OFF;

  // A staging: 2 gl_lds/wave/stage (layout/swizzle identical to r19)
  const unsigned short* xsrc[2];
  const unsigned short* hsrc[2];
#pragma unroll
  for (int j = 0; j < 2; ++j) {
    const int ci = (wid * 2 + j) * 64 + lane;      // 0..511
    const int r  = ci >> 2;                        // tile row 0..127
    const int sc = (ci & 3) ^ ((r >> 1) & 3);      // pre-swizzled chunk
    xsrc[j] = xb + (size_t)(mt * 128 + r) * 128 + sc * 8;
    hsrc[j] = hb + (size_t)(mt * 128 + r) * 256 + sc * 8;
  }
  const int ad0 = (wid * 2 + 0) * 1024;
  const int ad1 = (wid * 2 + 1) * 1024;

  // B staging: 4 gl_lds/wave/stage; local unit lu = wid*4+j (0..15),
  // lu = nb*8 + g*2 + kk; global unit = ((bnn*2+nb)*4+g)*24 + 2S+kk.
  const unsigned short* bsrc[4];
#pragma unroll
  for (int j = 0; j < 4; ++j) {
    const int lu = wid * 4 + j;
    const int nb = lu >> 3, g = (lu >> 1) & 3, kk = lu & 1;
    bsrc[j] = Bt + ((size_t)(((bnn * 2 + nb) * 4 + g) * 24) + kk) * 512 +
              lane * 8;
  }

  f32x16 acc[2][4];                      // [m][gate], 128 VGPR
#pragma unroll
  for (int m = 0; m < 2; ++m)
#pragma unroll
    for (int g = 0; g < 4; ++g)
#pragma unroll
      for (int e = 0; e < 16; ++e) acc[m][g][e] = 0.0f;

  float cvv[2][16];

  auto STAGE = [&](int T) {
    char* Ad = (char*)smem + ABUF(T % 3);
    char* Bd = (char*)smem + BBUF(T % 3);
    if (T < 4) {
      gl16(xsrc[0] + T * 32, Ad + ad0);
      gl16(xsrc[1] + T * 32, Ad + ad1);
    } else {
      gl16(hsrc[0] + (T - 4) * 32, Ad + ad0);
      gl16(hsrc[1] + (T - 4) * 32, Ad + ad1);
    }
#pragma unroll
    for (int j = 0; j < 4; ++j)
      gl16(bsrc[j] + T * 1024, Bd + (wid * 4 + j) * 1024);
  };

  auto COMPUTE = [&](int S) {
    const unsigned short* Ab = (const unsigned short*)(smem + ABUF(S % 3));
    const unsigned short* Bb = (const unsigned short*)(smem + BBUF(S % 3));
#pragma unroll
    for (int kk = 0; kk < 2; ++kk) {
      bf16x8 afr[2], bfr[4];
#pragma unroll
      for (int m = 0; m < 2; ++m) {
        const int row   = wr * 64 + m * 32 + l31;
        const int chunk = (kk * 2 + kh) ^ sx;
        afr[m] = *reinterpret_cast<const bf16x8*>(Ab + row * 32 + chunk * 8);
      }
#pragma unroll
      for (int g = 0; g < 4; ++g) {
        const int u = wc * 8 + g * 2 + kk;
        bfr[g] = *reinterpret_cast<const bf16x8*>(Bb + u * 512 + lane * 8);
      }
#pragma unroll
      for (int m = 0; m < 2; ++m)
#pragma unroll
        for (int g = 0; g < 4; ++g)
          acc[m][g] = __builtin_amdgcn_mfma_f32_32x32x16_bf16(
              afr[m], bfr[g], acc[m][g], 0, 0, 0);
    }
  };

  // prologue: 2 stages (12 gl_lds) in flight
  STAGE(0);
  STAGE(1);

  // FIFO (6 gl_lds/stage/wave): steady VMW(6). C (32 loads) issued at end of
  // step 8 (after STAGE(10)):
  //   step 9 top:  outstanding S9,S10,C        -> need S9  -> VMW(38)
  //   step 10 top: outstanding S10,C,S11       -> need S10 -> VMW(38)
  //   step 11 top: outstanding C,S11           -> need S11 -> VMW(0)
#define STEP(S, KN)                                                \
  do {                                                             \
    VMW(KN);                                                       \
    __builtin_amdgcn_s_barrier();                                  \
    if ((S) + 2 < 12) STAGE((S) + 2);                              \
    if ((S) == 8) {                                                \
      const float* cb =                                            \
          Cin + ((size_t)mt * 128 + wr * 64 + 4 * kh) * HDIM + ch; \
      _Pragma("unroll")                                            \
      for (int m = 0; m < 2; ++m)                                  \
        _Pragma("unroll")                                          \
        for (int rg = 0; rg < 16; ++rg) {                          \
          const int roff = m * 32 + (rg & 3) + 8 * (rg >> 2);      \
          cvv[m][rg] = __builtin_nontemporal_load(                 \
              cb + (size_t)roff * HDIM);                           \
        }                                                          \
    }                                                              \
    COMPUTE(S);                                                    \
  } while (0)

  STEP(0, 6);  STEP(1, 6);  STEP(2, 6);  STEP(3, 6);
  STEP(4, 6);  STEP(5, 6);  STEP(6, 6);  STEP(7, 6);
  STEP(8, 6);  STEP(9, 38); STEP(10, 38); STEP(11, 0);
#undef STEP

  // ---- epilogue: bias folded in acc; lane-local gate combine --------------
  // D: col = lane&31, row = (reg&3) + 8*(reg>>2) + 4*kh (+ m*32)
  // -> 32 consecutive lanes store 128B full lines.
  float* op  = out + ((size_t)mt * 128 + wr * 64 + 4 * kh) * HDIM + ch;
  float* op2 = op + (size_t)NROWS * HDIM;
#pragma unroll
  for (int m = 0; m < 2; ++m) {
#pragma unroll
    for (int rg = 0; rg < 16; ++rg) {
      const int roff = m * 32 + (rg & 3) + 8 * (rg >> 2);
      const float pi = acc[m][0][rg];
      const float pf = acc[m][1][rg];
      const float pg = acc[m][2][rg];
      const float po = acc[m][3][rg];
      const float ig = sigm(pi), fg = sigm(pf);
      const float gg = tanh_fast(pg), og = sigm(po);
      const float co = fg * cvv[m][rg] + ig * gg;
      const float ho = og * tanh_fast(co);
      __builtin_nontemporal_store(co, op  + (size_t)roff * HDIM);
      __builtin_nontemporal_store(ho, op2 + (size_t)roff * HDIM);
    }
  }
}

extern "C" void kernel_launch(void* const* d_in, const int* in_sizes, int n_in,
                              void* d_out, int out_size, void* d_ws, size_t ws_size,
                              hipStream_t stream) {
  const float* x  = (const float*)d_in[0];
  const float* C  = (const float*)d_in[1];
  const float* h  = (const float*)d_in[2];
  const float* Wx = (const float*)d_in[3];
  const float* Wh = (const float*)d_in[4];
  const float* bx = (const float*)d_in[5];
  const float* bh = (const float*)d_in[6];
  float* o = (float*)d_out;
  unsigned short* ws = (unsigned short*)d_ws;   // ~98 MiB used

  prep_all<<<dim3(24768), dim3(256), 0, stream>>>(x, h, Wx, Wh, bx, bh, ws);
  lstm_main<<<dim3(4096), dim3(256), 0, stream>>>(ws, C, o);
}